// Round 1
// baseline (171.615 us; speedup 1.0000x reference)
//
#include <hip/hip_runtime.h>
#include <cstdint>
#include <cstddef>

// Problem shape (fixed by setup_inputs): hidden [4,2048,2048] -> M=8192, K=2048, N=2048
#define MDIM 8192
#define NDIM 2048
#define KDIM 2048

constexpr int BM = 256, BN = 256, BK = 64;   // 256^2 tile, 4-deep LDS ring = 128 KB
constexpr int NT = KDIM / BK;                // 32 k-tiles
constexpr int NBUF = 4;

typedef int v4i __attribute__((ext_vector_type(4)));

__device__ __forceinline__ void async_ld16(const void* g, void* l) {
    __builtin_amdgcn_global_load_lds(
        (const __attribute__((address_space(1))) int*)g,
        (__attribute__((address_space(3))) int*)l,
        16, 0, 0);
}

// ---------- fused quantize: x fp32 -> int8 (packed u32)  +  W fp32 [K][N] -> int8 [N][K] ----------
__device__ __forceinline__ uint32_t q8(float x, float inv) {
    float q = fminf(fmaxf(rintf(x * inv), -127.f), 127.f);
    return (uint32_t)((int)q) & 0xffu;
}

#define XBLOCKS (MDIM * KDIM / 4 / 256)   // 16384 blocks for the x-part

__global__ void quant_kernel(const float4* __restrict__ x, uint32_t* __restrict__ xq,
                             const float* __restrict__ scale_p,
                             const float* __restrict__ w, uint32_t* __restrict__ wt) {
    __shared__ uint32_t t[64][17];
    const int tid = threadIdx.x;

    if (blockIdx.x < XBLOCKS) {
        // ---- x quant: one float4 -> 4 int8, fully coalesced ----
        int i = blockIdx.x * 256 + tid;
        float inv = 1.0f / fmaxf(scale_p[0], 1e-8f);
        float4 v = x[i];
        xq[i] = q8(v.x, inv) | (q8(v.y, inv) << 8) | (q8(v.z, inv) << 16) | (q8(v.w, inv) << 24);
        return;
    }

    // ---- W quant + transpose: 64x64 tile per block ----
    const int bid = blockIdx.x - XBLOCKS;          // 0..1023
    const int k0 = (bid >> 5) * 64;                // KDIM/64 = 32
    const int n0 = (bid & 31) * 64;                // NDIM/64 = 32
    const int rr  = tid >> 4;                      // 0..15
    const int c4  = (tid & 15) * 4;                // 0..60
#pragma unroll
    for (int p = 0; p < 4; ++p) {
        int r = rr + p * 16;
        float4 v = *(const float4*)&w[(size_t)(k0 + r) * NDIM + n0 + c4];
        uint32_t pk = (uint32_t)((int)rintf(v.x) & 0xff)
                    | ((uint32_t)((int)rintf(v.y) & 0xff) << 8)
                    | ((uint32_t)((int)rintf(v.z) & 0xff) << 16)
                    | ((uint32_t)((int)rintf(v.w) & 0xff) << 24);
        t[r][c4 >> 2] = pk;
    }
    __syncthreads();
#pragma unroll
    for (int p = 0; p < 4; ++p) {
        int c = rr + p * 16;
        uint32_t o = 0;
#pragma unroll
        for (int j = 0; j < 4; ++j) {
            uint32_t b = (t[c4 + j][c >> 2] >> ((c & 3) * 8)) & 0xffu;
            o |= b << (j * 8);
        }
        wt[((size_t)(n0 + c) * KDIM + k0 + c4) >> 2] = o;
    }
}

// ---------- i8 GEMM: C = A * Bt^T + bias; 256^2 tile, 4-deep ring, counted vmcnt ----------
// LDS tile row = 64B = 4 x 16B chunks; chunk c of row r stored at slot c ^ ((r>>1)&3)
// (verified conflict-free: SQ_LDS_BANK_CONFLICT == 0 on the 128^2 predecessor).
__global__ __launch_bounds__(512, 2)
void gemm_i8_kernel(const int8_t* __restrict__ A,   // [M][K] int8
                    const int8_t* __restrict__ Bt,  // [N][K] int8
                    const float* __restrict__ bias, // [N]
                    float* __restrict__ C) {        // [M][N] fp32
    __shared__ alignas(16) int8_t lA[NBUF][BM * BK];   // 4 x 16 KB
    __shared__ alignas(16) int8_t lB[NBUF][BN * BK];   // 4 x 16 KB

    const int tid  = threadIdx.x;
    const int lane = tid & 63;
    const int wave = tid >> 6;           // 0..7
    const int wm   = wave & 1;           // M-half: 128 rows
    const int wn   = wave >> 1;          // N-quarter: 64 cols

    // XCD-aware swizzle: 256 blocks, 8 XCDs -> each XCD gets 4 M-panels x all 8 N-panels
    const int bidlin = blockIdx.y * gridDim.x + blockIdx.x;   // 0..255
    const int swz    = (bidlin & 7) * 32 + (bidlin >> 3);
    const int m0     = (swz >> 3) * BM;
    const int n0     = (swz & 7) * BN;

    // staging: wave covers 32 rows (srow, srow+16), 4 async loads / thread / tile
    const int srow = lane >> 2;                       // 0..15
    const int schk = (lane & 3) ^ ((srow >> 1) & 3);  // swizzled source chunk
    const int8_t* gA = A  + (size_t)(m0 + wave * 32 + srow) * KDIM + schk * 16;
    const int8_t* gB = Bt + (size_t)(n0 + wave * 32 + srow) * KDIM + schk * 16;
    const int lwo = wave * 2048;

    // fragments: lane reads row (.. + lr), logical chunk quad at slot quad^((lr>>1)&3)
    const int quad = lane >> 4;
    const int lr   = lane & 15;
    const int fchk = (quad ^ ((lr >> 1) & 3)) * 16;
    const int aoff = (wm * 128 + lr) * BK + fchk;
    const int boff = (wn * 64 + lr) * BK + fchk;

    v4i acc[8][4];
#pragma unroll
    for (int i = 0; i < 8; ++i)
#pragma unroll
        for (int j = 0; j < 4; ++j)
            acc[i][j] = (v4i){0, 0, 0, 0};

#define STAGE(buf, kof)                                                        \
    do {                                                                       \
        async_ld16(gA + (kof), &lA[buf][lwo]);                                 \
        async_ld16(gA + (kof) + (size_t)16 * KDIM, &lA[buf][lwo + 1024]);      \
        async_ld16(gB + (kof), &lB[buf][lwo]);                                 \
        async_ld16(gB + (kof) + (size_t)16 * KDIM, &lB[buf][lwo + 1024]);      \
    } while (0)

#define COMPUTE(buf)                                                           \
    do {                                                                       \
        v4i bf[4];                                                             \
        _Pragma("unroll")                                                      \
        for (int j = 0; j < 4; ++j)                                            \
            bf[j] = *(const v4i*)&lB[buf][boff + j * 1024];                    \
        __builtin_amdgcn_s_setprio(1);                                         \
        _Pragma("unroll")                                                      \
        for (int i = 0; i < 8; ++i) {                                          \
            v4i af = *(const v4i*)&lA[buf][aoff + i * 1024];                   \
            _Pragma("unroll")                                                  \
            for (int j = 0; j < 4; ++j)                                        \
                acc[i][j] = __builtin_amdgcn_mfma_i32_16x16x64_i8(             \
                    af, bf[j], acc[i][j], 0, 0, 0);                            \
        }                                                                      \
        __builtin_amdgcn_s_setprio(0);                                        \
    } while (0)

#define WAITBAR(n)                                                             \
    do {                                                                       \
        asm volatile("s_waitcnt vmcnt(" #n ")" ::: "memory");                  \
        __builtin_amdgcn_s_barrier();                                          \
        asm volatile("" ::: "memory");                                         \
    } while (0)

    // prologue: fill 3 stages of the ring (12 loads in flight max)
    STAGE(0, 0);
    STAGE(1, BK);
    STAGE(2, 2 * BK);

    // main loop: t = 0..NT-4; stage t+3 after the barrier (buf (t+3)&3, readers done)
    int kof = 3 * BK;
    for (int t = 0; t < NT - 3; ++t) {
        WAITBAR(8);                      // tiles t+1,t+2 may stay in flight; tile t landed
        STAGE((t + 3) & 3, kof);
        kof += BK;
        COMPUTE(t & 3);
    }
    // tail: t = NT-3, NT-2, NT-1 with derived waits 8 -> 4 -> 0
    WAITBAR(8);
    COMPUTE((NT - 3) & 3);
    WAITBAR(4);
    COMPUTE((NT - 2) & 3);
    WAITBAR(0);
    COMPUTE((NT - 1) & 3);

#undef STAGE
#undef COMPUTE
#undef WAITBAR

    // epilogue: C/D layout col = lane&15, row = quad*4 + reg (verified, dtype-indep)
    const int crow = m0 + wm * 128 + quad * 4;
    const int ccol = n0 + wn * 64 + lr;
    float bj[4];
#pragma unroll
    for (int j = 0; j < 4; ++j) bj[j] = bias[ccol + j * 16];
#pragma unroll
    for (int i = 0; i < 8; ++i)
#pragma unroll
        for (int j = 0; j < 4; ++j)
#pragma unroll
            for (int r = 0; r < 4; ++r)
                C[(size_t)(crow + i * 16 + r) * NDIM + (ccol + j * 16)] = (float)acc[i][j][r] + bj[j];
}

extern "C" void kernel_launch(void* const* d_in, const int* in_sizes, int n_in,
                              void* d_out, int out_size, void* d_ws, size_t ws_size,
                              hipStream_t stream) {
    const float* x    = (const float*)d_in[0];   // [8192, 2048] fp32
    const float* w    = (const float*)d_in[1];   // [2048, 2048] fp32 (integer-valued)
    const float* xs   = (const float*)d_in[2];   // scalar
    const float* bias = (const float*)d_in[3];   // [2048]
    float* out = (float*)d_out;                  // [8192, 2048] fp32

    int8_t* xq = (int8_t*)d_ws;                          // 16 MB
    int8_t* wt = xq + (size_t)MDIM * KDIM;               //  4 MB

    quant_kernel<<<XBLOCKS + (KDIM / 64) * (NDIM / 64), 256, 0, stream>>>(
        (const float4*)x, (uint32_t*)xq, xs, w, (uint32_t*)wt);
    gemm_i8_kernel<<<dim3(NDIM / BN, MDIM / BM), 512, 0, stream>>>(xq, wt, bias, out);
}